// Round 9
// baseline (173.547 us; speedup 1.0000x reference)
//
#include <hip/hip_runtime.h>
#include <hip/hip_fp16.h>
#include <math.h>

// Problem dims
#define B_ 8
#define H_ 640
#define W_ 368
#define HW_ (H_*W_)
#define NP_ (B_*H_*W_)   // 1,884,160

#define WLINES 8         // lines per block in W-axis FFT
#define HCOLS 4          // columns per block in H-axis FFT
#define TS 16            // spatial tile for fused tail kernel

typedef __attribute__((ext_vector_type(8))) short v8s;   // 8 bf16 (4 VGPR)
typedef __attribute__((ext_vector_type(4))) float v4f;   // MFMA acc

__device__ __forceinline__ float leaky_(float x){ return fmaxf(x, 0.01f*x); }

// fp32 -> bf16 round-to-nearest-even
__device__ __forceinline__ unsigned short f2bf(float x){
    unsigned u = __float_as_uint(x);
    u += 0x7FFFu + ((u >> 16) & 1u);
    return (unsigned short)(u >> 16);
}

__device__ __forceinline__ float2 cadd_(float2 a, float2 b){ return make_float2(a.x+b.x, a.y+b.y); }
__device__ __forceinline__ float2 csub_(float2 a, float2 b){ return make_float2(a.x-b.x, a.y-b.y); }
__device__ __forceinline__ float2 cmul_(float2 a, float c, float s){
    return make_float2(a.x*c - a.y*s, a.x*s + a.y*c);
}
__device__ __forceinline__ float2 cmulv_(float2 a, float2 w){
    return make_float2(a.x*w.x - a.y*w.y, a.x*w.y + a.y*w.x);
}

// DFT4 with +i convention
__device__ __forceinline__ void dft4p_(float2 p0, float2 p1, float2 p2, float2 p3,
                                       float2& z0, float2& z1, float2& z2, float2& z3){
    float2 s0 = cadd_(p0,p2), d0 = csub_(p0,p2);
    float2 s1 = cadd_(p1,p3), d1 = csub_(p1,p3);
    z0 = cadd_(s0,s1);
    z2 = csub_(s0,s1);
    z1 = make_float2(d0.x - d1.y, d0.y + d1.x);
    z3 = make_float2(d0.x + d1.y, d0.y - d1.x);
}

// 16-point DFT, +i convention
__device__ __forceinline__ void fft16p_(const float2* x, float2* X){
    const float C1 = 0.9238795325112867f, S1 = 0.3826834323650898f;
    const float R  = 0.7071067811865476f;
    float2 Y[4][4];
    #pragma unroll
    for (int b = 0; b < 4; ++b)
        dft4p_(x[b], x[4+b], x[8+b], x[12+b], Y[b][0], Y[b][1], Y[b][2], Y[b][3]);
    Y[1][1] = cmul_(Y[1][1],  C1,  S1);
    Y[1][2] = cmul_(Y[1][2],   R,   R);
    Y[1][3] = cmul_(Y[1][3],  S1,  C1);
    Y[2][1] = cmul_(Y[2][1],   R,   R);
    Y[2][2] = make_float2(-Y[2][2].y, Y[2][2].x);
    Y[2][3] = cmul_(Y[2][3],  -R,   R);
    Y[3][1] = cmul_(Y[3][1],  S1,  C1);
    Y[3][2] = cmul_(Y[3][2],  -R,   R);
    Y[3][3] = cmul_(Y[3][3], -C1, -S1);
    #pragma unroll
    for (int c = 0; c < 4; ++c)
        dft4p_(Y[0][c], Y[1][c], Y[2][c], Y[3][c], X[c], X[c+4], X[c+8], X[c+12]);
}

// 8-point DFT, +i convention
__device__ __forceinline__ void fft8p_(const float2* x, float2* X){
    const float R = 0.7071067811865476f;
    float2 Y0[4], Y1[4];
    dft4p_(x[0], x[2], x[4], x[6], Y0[0], Y0[1], Y0[2], Y0[3]);
    dft4p_(x[1], x[3], x[5], x[7], Y1[0], Y1[1], Y1[2], Y1[3]);
    float2 T0 = Y1[0];
    float2 T1 = cmul_(Y1[1],  R, R);
    float2 T2 = make_float2(-Y1[2].y, Y1[2].x);
    float2 T3 = cmul_(Y1[3], -R, R);
    X[0] = cadd_(Y0[0], T0);  X[4] = csub_(Y0[0], T0);
    X[1] = cadd_(Y0[1], T1);  X[5] = csub_(Y0[1], T1);
    X[2] = cadd_(Y0[2], T2);  X[6] = csub_(Y0[2], T2);
    X[3] = cadd_(Y0[3], T3);  X[7] = csub_(Y0[3], T3);
}

// ---------------------------------------------------------------------------
// Tables (float2 indices in T):
//   TW368P @    0 (368)  [n2*16+k1] = e^{+2pi i k1 n2/368}
//   TW640P @  368 (640)  [n2*16+k1] = e^{+2pi i k1 n2/640}
//   TW40P  @ 1008 ( 40)  [m2*8+j1]  = e^{+2pi i j1 m2/40}
//   F23P   @ 1048 (253)  [k2*11+m-1]= (cos,sin)(2pi k2 m/23)
// ---------------------------------------------------------------------------
__global__ void init_tables_kernel(float2* __restrict__ T){
    int i = blockIdx.x*blockDim.x + threadIdx.x;
    if (i >= 1301) return;
    int r, c, modN; int j;
    if      (i <  368){ j = i;        r = j%16; c = j/16; modN = 368; }
    else if (i < 1008){ j = i-368;    r = j%16; c = j/16; modN = 640; }
    else if (i < 1048){ j = i-1008;   r = j%8;  c = j/8;  modN = 40;  }
    else              { j = i-1048;   r = j/11; c = j%11 + 1; modN = 23; }
    int t = (int)(((long long)r * c) % modN);
    if (t > modN/2) t -= modN;
    float ang = (float)(6.283185307179586 * ((double)t / (double)modN));
    float s, co;
    sincosf(ang, &s, &co);
    T[i] = make_float2(co, s);
}

// ---------------------------------------------------------------------------
// K1 (MFMA v2): fused k-branch. One block per (b,h) row.
//  Phase A: direct global->LDS im2col M[px][k] (bf16, stride 40 ushorts).
//           threads 0..143: k = t>>3 (fixed), walk px by 8.
//           threads 144..255: zero k = 18..31 (MFMA garbage*0 can be NaN).
//  Phase B per wave-owned 16-px group:
//    af  = ds_read_b128 (px = g*16 + lane&15, k-slice q*8..q*8+7)
//    2x MFMA (oc 0..15, 16..31) -> bias+leaky -> packed ds_write_b32 into the
//    SAME px slots with interleaved k' (l0->2oc, l1->2oc+1); permutation is
//    folded into the 1x1 B-frag. Slot reuse is wave-local (wave owns its px).
//    a2 = ds_read_b128 -> MFMA (1x1, K=32) -> bias+leaky -> float2 store.
//  All LDS addresses land <=2-way bank aliasing (free on gfx950).
// ---------------------------------------------------------------------------
__global__ __launch_bounds__(256) void kbranch_mfma(const float* __restrict__ ksp,
                               const float* __restrict__ wk,
                               const float* __restrict__ bk,
                               const float* __restrict__ w1,
                               const float* __restrict__ b1,
                               float2* __restrict__ A){
    __shared__ unsigned short M[368*40];    // 29,440 B
    int t = threadIdx.x;
    int bh = blockIdx.x;                    // b*640 + h
    int h = bh % 640, b = bh / 640;
    int lane = t & 63, wave = t >> 6;
    int n = lane & 15, q = lane >> 4;

    // weight fragments (B-layout: lane holds B[k=q*8+j][n=lane&15])
    v8s bf0, bf1, b2f;
    #pragma unroll
    for (int j = 0; j < 8; ++j){
        int kk = q*8 + j;
        float v0 = (kk < 18) ? wk[n*18 + kk]      : 0.f;
        float v1 = (kk < 18) ? wk[(n+16)*18 + kk] : 0.f;
        bf0[j] = (short)f2bf(v0);
        bf1[j] = (short)f2bf(v1);
        int ko = (kk & 1) ? 16 + (kk >> 1) : (kk >> 1);   // inverse interleave
        b2f[j] = (n < 2) ? (short)f2bf(w1[n*32 + ko]) : (short)0;
    }
    float bk0 = bk[n], bk1 = bk[n+16];
    float biasn = (n == 1) ? b1[1] : b1[0];

    // Phase A: im2col + zero-pad
    if (t < 144){
        int kk = t >> 3, px0 = t & 7;
        int ic = (kk >= 9) ? 1 : 0;
        int tt = kk - 9*ic;
        int ty = tt / 3, tx = tt - 3*ty;
        int hh = h - 1 + ty;
        float rvf = ((unsigned)hh < 640u) ? 1.f : 0.f;
        int hhc = min(max(hh, 0), 639);
        const float* base = ksp + ((size_t)(b*2 + ic)*640 + hhc)*368;
        int txo = tx - 1;
        for (int px = px0; px < 368; px += 8){
            int c = px + txo;
            float msk = ((unsigned)c < 368u) ? rvf : 0.f;
            int cc = min(max(c, 0), 367);
            M[px*40 + kk] = f2bf(base[cc] * msk);
        }
    } else {
        int kk = 18 + ((t - 144) >> 3), px0 = (t - 144) & 7;
        for (int px = px0; px < 368; px += 8)
            M[px*40 + kk] = 0;
    }
    __syncthreads();

    int gbase = wave*6;
    int cnt = (wave < 3) ? 6 : 5;           // 23 groups of 16 px
    for (int i = 0; i < cnt; ++i){
        int g = gbase + i;
        int pxa = g*16 + n;                 // A row for this lane
        const v8s af = *(const v8s*)(M + pxa*40 + q*8);
        v4f d0 = {0.f,0.f,0.f,0.f}, d1 = {0.f,0.f,0.f,0.f};
        d0 = __builtin_amdgcn_mfma_f32_16x16x32_bf16(af, bf0, d0, 0, 0, 0);
        d1 = __builtin_amdgcn_mfma_f32_16x16x32_bf16(af, bf1, d1, 0, 0, 0);
        // bias + leaky + packed interleaved write-back (k' = 2n, 2n+1)
        #pragma unroll
        for (int r = 0; r < 4; ++r){
            int px = g*16 + q*4 + r;
            float l0 = leaky_(d0[r] + bk0);
            float l1 = leaky_(d1[r] + bk1);
            unsigned pk = ((unsigned)f2bf(l1) << 16) | (unsigned)f2bf(l0);
            *(unsigned*)(M + px*40 + 2*n) = pk;
        }
        asm volatile("s_waitcnt lgkmcnt(0)" ::: "memory");  // writes -> a2 read
        const v8s a2 = *(const v8s*)(M + pxa*40 + q*8);
        v4f d2 = {0.f,0.f,0.f,0.f};
        d2 = __builtin_amdgcn_mfma_f32_16x16x32_bf16(a2, b2f, d2, 0, 0, 0);
        float vals[4], ov[4];
        #pragma unroll
        for (int r = 0; r < 4; ++r){
            vals[r] = leaky_(biasn + d2[r]);
            ov[r] = __shfl_xor(vals[r], 1);          // o1 (col 1) -> col-0 lane
        }
        if (n == 0){
            float2* dst = A + (size_t)bh*368 + g*16 + q*4;
            *(float4*)dst       = make_float4(vals[0], ov[0], vals[1], ov[1]);
            *(float4*)(dst + 2) = make_float4(vals[2], ov[2], vals[3], ov[3]);
        }
    }
}

// ---------------------------------------------------------------------------
// K2: W-axis centered IFFT, W = 368 = 16*23.  8 lines/block, 640 blocks.
// ---------------------------------------------------------------------------
__global__ __launch_bounds__(256) void fftW_kernel(const float2* __restrict__ A,
                                                   const float2* __restrict__ TW368P,
                                                   const float2* __restrict__ F23P,
                                                   float2* __restrict__ Bo){
    __shared__ float2 X[WLINES*369];      // 23,616 B
    int t = threadIdx.x;
    size_t base = (size_t)blockIdx.x * (WLINES*368);

    for (int i = t; i < WLINES*368; i += 256){
        int l = i / 368, n = i - l*368;
        float2 v = A[base + i];
        float s = (i & 1) ? -1.f : 1.f;            // (-1)^n
        X[l*369 + n] = make_float2(v.x*s, v.y*s);
    }
    __syncthreads();

    // stage 1: items (l,n2) = 184
    if (t < 184){
        int l = t & 7, n2 = t >> 3;
        float2 xr[16], Xo[16];
        #pragma unroll
        for (int n1 = 0; n1 < 16; ++n1) xr[n1] = X[l*369 + 23*n1 + n2];
        fft16p_(xr, Xo);
        const float2* row = TW368P + n2*16;
        #pragma unroll
        for (int k1 = 0; k1 < 16; ++k1)
            X[l*369 + 23*k1 + n2] = cmulv_(Xo[k1], row[k1]);
    }
    __syncthreads();

    // stage 2: DFT23 via pairs; 256 units = (l,k1,half)
    {
        int l = t & 7, k1 = (t >> 3) & 15, half = t >> 7;
        const float2* xp = X + l*369 + 23*k1;
        float2 x0 = xp[0];
        float2 u[11], d[11];
        #pragma unroll
        for (int m = 1; m <= 11; ++m){
            float2 a = xp[m], bb = xp[23-m];
            u[m-1] = cadd_(a, bb);
            d[m-1] = csub_(a, bb);
        }
        __syncthreads();
        int k2beg = half ? 12 : 0;
        int k2end = half ? 23 : 12;
        for (int k2 = k2beg; k2 < k2end; ++k2){
            const float2* row = F23P + k2*11;      // wave-uniform -> s_load
            float re = x0.x, im = x0.y;
            #pragma unroll
            for (int m = 0; m < 11; ++m){
                float c = row[m].x, s = row[m].y;
                re += u[m].x*c - d[m].y*s;
                im += u[m].y*c + d[m].x*s;
            }
            X[l*369 + k1 + 16*k2] = make_float2(re, im);
        }
    }
    __syncthreads();

    const float sc = 0.052129458158616354f;        // 1/sqrt(368)
    for (int i = t; i < WLINES*368; i += 256){
        int l = i / 368, k = i - l*368;
        float2 v = X[l*369 + k];
        float s = (i & 1) ? -sc : sc;              // (-1)^k
        Bo[base + i] = make_float2(v.x*s, v.y*s);
    }
}

// ---------------------------------------------------------------------------
// K3: H-axis centered IFFT, H = 640 = 16*8*5.  4 cols/block, 736 blocks.
// ---------------------------------------------------------------------------
__global__ __launch_bounds__(256) void fftH_kernel(const float2* __restrict__ Bi,
                                                   const float2* __restrict__ TW640P,
                                                   const float2* __restrict__ TW40P,
                                                   float2* __restrict__ Ao){
    __shared__ float2 X[640*5];           // 25,600 B
    int t = threadIdx.x;
    int b  = blockIdx.x / 92;
    int w0 = (blockIdx.x - b*92) * HCOLS;
    const float2* src = Bi + (size_t)b*HW_ + w0;

    for (int i = t; i < 640*HCOLS; i += 256){
        int n = i >> 2, c = i & 3;
        float2 v = src[(size_t)n*W_ + c];
        float s = (n & 1) ? -1.f : 1.f;            // (-1)^n
        X[n*5 + c] = make_float2(v.x*s, v.y*s);
    }
    __syncthreads();

    // stage 1: items (c,n2) = 160
    if (t < 160){
        int c = t & 3, n2 = t >> 2;
        float2 xr[16], Xo[16];
        #pragma unroll
        for (int n1 = 0; n1 < 16; ++n1) xr[n1] = X[(40*n1 + n2)*5 + c];
        fft16p_(xr, Xo);
        const float2* row = TW640P + n2*16;
        #pragma unroll
        for (int k1 = 0; k1 < 16; ++k1)
            X[(40*k1 + n2)*5 + c] = cmulv_(Xo[k1], row[k1]);
    }
    __syncthreads();

    // stage 2a: FFT8 over m1, items (c,k1,m2) = 320
    for (int it = t; it < 320; it += 256){
        int c = it & 3, k1 = (it >> 2) & 15, m2 = it >> 6;
        float2 xr[8], Xo[8];
        #pragma unroll
        for (int m1 = 0; m1 < 8; ++m1) xr[m1] = X[(40*k1 + 5*m1 + m2)*5 + c];
        fft8p_(xr, Xo);
        const float2* row = TW40P + m2*8;
        #pragma unroll
        for (int j1 = 0; j1 < 8; ++j1)
            X[(40*k1 + 5*j1 + m2)*5 + c] = cmulv_(Xo[j1], row[j1]);
    }
    __syncthreads();

    // stage 2b: DFT5 over m2 via pairs, items (c,k1,j1) = 512 -> 2/thread
    {
        const float CK1[5] = {1.f,  0.30901699437494745f, -0.8090169943749475f, -0.8090169943749475f,  0.30901699437494745f};
        const float SK1[5] = {0.f,  0.9510565162951535f,   0.5877852522924731f, -0.5877852522924731f, -0.9510565162951535f};
        const float CK2[5] = {1.f, -0.8090169943749475f,   0.30901699437494745f, 0.30901699437494745f, -0.8090169943749475f};
        const float SK2[5] = {0.f,  0.5877852522924731f,  -0.9510565162951535f,  0.9510565162951535f, -0.5877852522924731f};
        int it0 = t, it1 = t + 256;
        int c0 = it0 & 3, k10 = (it0 >> 2) & 15, j10 = it0 >> 6;
        int c1 = it1 & 3, k11 = (it1 >> 2) & 15, j11 = it1 >> 6;
        float2 p0[5], p1[5];
        #pragma unroll
        for (int m2 = 0; m2 < 5; ++m2) p0[m2] = X[(40*k10 + 5*j10 + m2)*5 + c0];
        #pragma unroll
        for (int m2 = 0; m2 < 5; ++m2) p1[m2] = X[(40*k11 + 5*j11 + m2)*5 + c1];
        __syncthreads();
        float2 u0a = cadd_(p0[1], p0[4]), d0a = csub_(p0[1], p0[4]);
        float2 u0b = cadd_(p0[2], p0[3]), d0b = csub_(p0[2], p0[3]);
        float2 u1a = cadd_(p1[1], p1[4]), d1a = csub_(p1[1], p1[4]);
        float2 u1b = cadd_(p1[2], p1[3]), d1b = csub_(p1[2], p1[3]);
        #pragma unroll
        for (int j2 = 0; j2 < 5; ++j2){
            float c1v = CK1[j2], s1v = SK1[j2], c2v = CK2[j2], s2v = SK2[j2];
            float re0 = p0[0].x + u0a.x*c1v - d0a.y*s1v + u0b.x*c2v - d0b.y*s2v;
            float im0 = p0[0].y + u0a.y*c1v + d0a.x*s1v + u0b.y*c2v + d0b.x*s2v;
            float re1 = p1[0].x + u1a.x*c1v - d1a.y*s1v + u1b.x*c2v - d1b.y*s2v;
            float im1 = p1[0].y + u1a.y*c1v + d1a.x*s1v + u1b.y*c2v + d1b.x*s2v;
            X[(k10 + 16*j10 + 128*j2)*5 + c0] = make_float2(re0, im0);
            X[(k11 + 16*j11 + 128*j2)*5 + c1] = make_float2(re1, im1);
        }
    }
    __syncthreads();

    const float sc = 0.03952847075210474f;         // 1/sqrt(640)
    float2* dst = Ao + (size_t)b*HW_ + w0;
    for (int i = t; i < 640*HCOLS; i += 256){
        int k = i >> 2, c = i & 3;
        float2 v = X[k*5 + c];
        float s = (k & 1) ? -sc : sc;              // (-1)^k
        dst[(size_t)k*W_ + c] = make_float2(v.x*s, v.y*s);
    }
}

// ---------------------------------------------------------------------------
// K4 (fused tail): B-axis FFT8 + magnitude + fp16-emulated conv2(1x1) + leaky
//                  + conv3x3(1->1, pad1) + leaky -> d_out.
// ---------------------------------------------------------------------------
__global__ __launch_bounds__(256) void tail_kernel(const float2* __restrict__ A,
                                  const float* __restrict__ img,
                                  const float* __restrict__ w2,
                                  const float* __restrict__ b2,
                                  const float* __restrict__ wi,
                                  const float* __restrict__ bi,
                                  float* __restrict__ out){
    __shared__ float Pl[8][TS+2][TS+2];            // 10,368 B
    int t = threadIdx.x;
    int ty0 = (blockIdx.x / 23) * TS;              // 40 tiles over h
    int tx0 = (blockIdx.x % 23) * TS;              // 23 tiles over w

    float w2h0 = __half2float(__float2half(w2[0]));
    float w2h1 = __half2float(__float2half(w2[1]));
    float b2h  = __half2float(__float2half(b2[0]));
    const float sc8 = 0.35355339059327373f;        // 1/sqrt(8)

    // stage 1: fill P tile with halo (324 items)
    for (int idx = t; idx < (TS+2)*(TS+2); idx += 256){
        int hy = idx / (TS+2), hx = idx - hy*(TS+2);
        int hh = ty0 - 1 + hy, ww = tx0 - 1 + hx;
        bool inb = (hh >= 0) && (hh < H_) && (ww >= 0) && (ww < W_);
        int hc = min(max(hh, 0), H_-1), wc = min(max(ww, 0), W_-1);
        int hw = hc*W_ + wc;
        float2 x[8], Xo[8];
        #pragma unroll
        for (int n = 0; n < 8; ++n){
            float2 v = A[(size_t)n*HW_ + hw];
            float s = (n & 1) ? -1.f : 1.f;        // (-1)^n
            x[n] = make_float2(v.x*s, v.y*s);
        }
        fft8p_(x, Xo);
        float inbf = inb ? 1.f : 0.f;
        #pragma unroll
        for (int k = 0; k < 8; ++k){
            float s = (k & 1) ? -sc8 : sc8;        // (-1)^k / sqrt(8)
            float yr = Xo[k].x * s, yi = Xo[k].y * s;
            float mag = sqrtf(yr*yr + yi*yi);
            float a = __half2float(__float2half(mag));
            float g = __half2float(__float2half(img[(size_t)k*HW_ + hw]));
            float o = a*w2h0 + g*w2h1 + b2h;
            o = leaky_(o);
            o = __half2float(__float2half(o));
            Pl[k][hy][hx] = o * inbf;              // zero-pad outside image
        }
    }
    __syncthreads();

    // stage 2: conv3x3 from LDS, 256 spatial px x 8 batch per block
    int sy = t >> 4, sx = t & 15;
    float wv[9];
    #pragma unroll
    for (int q = 0; q < 9; ++q) wv[q] = wi[q];
    float bi0 = bi[0];
    #pragma unroll
    for (int k = 0; k < 8; ++k){
        float acc = bi0;
        #pragma unroll
        for (int dy = 0; dy < 3; ++dy)
            #pragma unroll
            for (int dx = 0; dx < 3; ++dx)
                acc += wv[dy*3+dx] * Pl[k][sy+dy][sx+dx];
        out[((size_t)k*H_ + ty0+sy)*W_ + tx0+sx] = leaky_(acc);
    }
}

// ---------------------------------------------------------------------------
// Workspace layout (bytes):
//   A      : float2[NP]    @ 0            (15,073,280)
//   B      : float2[NP]    @ 15,073,280   (15,073,280)
//   tables : float2[1301]  @ 30,146,560   (10,408)
// ---------------------------------------------------------------------------
extern "C" void kernel_launch(void* const* d_in, const int* in_sizes, int n_in,
                              void* d_out, int out_size, void* d_ws, size_t ws_size,
                              hipStream_t stream){
    const float* img = (const float*)d_in[0];
    const float* ksp = (const float*)d_in[1];
    const float* wk  = (const float*)d_in[2];
    const float* bk  = (const float*)d_in[3];
    const float* w1  = (const float*)d_in[4];
    const float* b1  = (const float*)d_in[5];
    const float* w2  = (const float*)d_in[6];
    const float* b2  = (const float*)d_in[7];
    const float* wi  = (const float*)d_in[8];
    const float* bi  = (const float*)d_in[9];

    char* ws = (char*)d_ws;
    float2* A   = (float2*)(ws + 0);
    float2* Bb  = (float2*)(ws + 15073280);
    float2* T   = (float2*)(ws + 30146560);
    float2* TW368P = T + 0;
    float2* TW640P = T + 368;
    float2* TW40P  = T + 1008;
    float2* F23P   = T + 1048;
    float* out  = (float*)d_out;

    init_tables_kernel<<<6, 256, 0, stream>>>(T);

    kbranch_mfma<<<B_*H_, 256, 0, stream>>>(ksp, wk, bk, w1, b1, A);

    fftW_kernel<<<(B_*H_)/WLINES, 256, 0, stream>>>(A, TW368P, F23P, Bb);   // A -> B
    fftH_kernel<<<B_*(W_/HCOLS), 256, 0, stream>>>(Bb, TW640P, TW40P, A);   // B -> A

    tail_kernel<<<(H_/TS)*(W_/TS), 256, 0, stream>>>(A, img, w2, b2, wi, bi, out);
}

// Round 10
// 172.754 us; speedup vs baseline: 1.0046x; 1.0046x over previous
//
#include <hip/hip_runtime.h>
#include <hip/hip_fp16.h>
#include <math.h>

// Problem dims
#define B_ 8
#define H_ 640
#define W_ 368
#define HW_ (H_*W_)
#define NP_ (B_*H_*W_)   // 1,884,160

#define WLINES 8         // lines per block in W-axis FFT
#define HLINES 4         // (b,w) lines per block in H-axis FFT
#define HP 645           // LDS pitch (float2) for H kernel
#define TS 16            // spatial tile for fused tail kernel

typedef __attribute__((ext_vector_type(8))) short v8s;   // 8 bf16 (4 VGPR)
typedef __attribute__((ext_vector_type(4))) float v4f;   // MFMA acc

__device__ __forceinline__ float leaky_(float x){ return fmaxf(x, 0.01f*x); }

// fp32 -> bf16 round-to-nearest-even
__device__ __forceinline__ unsigned short f2bf(float x){
    unsigned u = __float_as_uint(x);
    u += 0x7FFFu + ((u >> 16) & 1u);
    return (unsigned short)(u >> 16);
}

__device__ __forceinline__ float2 cadd_(float2 a, float2 b){ return make_float2(a.x+b.x, a.y+b.y); }
__device__ __forceinline__ float2 csub_(float2 a, float2 b){ return make_float2(a.x-b.x, a.y-b.y); }
__device__ __forceinline__ float2 cmul_(float2 a, float c, float s){
    return make_float2(a.x*c - a.y*s, a.x*s + a.y*c);
}
__device__ __forceinline__ float2 cmulv_(float2 a, float2 w){
    return make_float2(a.x*w.x - a.y*w.y, a.x*w.y + a.y*w.x);
}

// DFT4 with +i convention
__device__ __forceinline__ void dft4p_(float2 p0, float2 p1, float2 p2, float2 p3,
                                       float2& z0, float2& z1, float2& z2, float2& z3){
    float2 s0 = cadd_(p0,p2), d0 = csub_(p0,p2);
    float2 s1 = cadd_(p1,p3), d1 = csub_(p1,p3);
    z0 = cadd_(s0,s1);
    z2 = csub_(s0,s1);
    z1 = make_float2(d0.x - d1.y, d0.y + d1.x);
    z3 = make_float2(d0.x + d1.y, d0.y - d1.x);
}

// 16-point DFT, +i convention
__device__ __forceinline__ void fft16p_(const float2* x, float2* X){
    const float C1 = 0.9238795325112867f, S1 = 0.3826834323650898f;
    const float R  = 0.7071067811865476f;
    float2 Y[4][4];
    #pragma unroll
    for (int b = 0; b < 4; ++b)
        dft4p_(x[b], x[4+b], x[8+b], x[12+b], Y[b][0], Y[b][1], Y[b][2], Y[b][3]);
    Y[1][1] = cmul_(Y[1][1],  C1,  S1);
    Y[1][2] = cmul_(Y[1][2],   R,   R);
    Y[1][3] = cmul_(Y[1][3],  S1,  C1);
    Y[2][1] = cmul_(Y[2][1],   R,   R);
    Y[2][2] = make_float2(-Y[2][2].y, Y[2][2].x);
    Y[2][3] = cmul_(Y[2][3],  -R,   R);
    Y[3][1] = cmul_(Y[3][1],  S1,  C1);
    Y[3][2] = cmul_(Y[3][2],  -R,   R);
    Y[3][3] = cmul_(Y[3][3], -C1, -S1);
    #pragma unroll
    for (int c = 0; c < 4; ++c)
        dft4p_(Y[0][c], Y[1][c], Y[2][c], Y[3][c], X[c], X[c+4], X[c+8], X[c+12]);
}

// 8-point DFT, +i convention
__device__ __forceinline__ void fft8p_(const float2* x, float2* X){
    const float R = 0.7071067811865476f;
    float2 Y0[4], Y1[4];
    dft4p_(x[0], x[2], x[4], x[6], Y0[0], Y0[1], Y0[2], Y0[3]);
    dft4p_(x[1], x[3], x[5], x[7], Y1[0], Y1[1], Y1[2], Y1[3]);
    float2 T0 = Y1[0];
    float2 T1 = cmul_(Y1[1],  R, R);
    float2 T2 = make_float2(-Y1[2].y, Y1[2].x);
    float2 T3 = cmul_(Y1[3], -R, R);
    X[0] = cadd_(Y0[0], T0);  X[4] = csub_(Y0[0], T0);
    X[1] = cadd_(Y0[1], T1);  X[5] = csub_(Y0[1], T1);
    X[2] = cadd_(Y0[2], T2);  X[6] = csub_(Y0[2], T2);
    X[3] = cadd_(Y0[3], T3);  X[7] = csub_(Y0[3], T3);
}

// ---------------------------------------------------------------------------
// Tables (float2 indices in T):
//   TW368P @    0 (368)  [n2*16+k1] = e^{+2pi i k1 n2/368}
//   TW640P @  368 (640)  [n2*16+k1] = e^{+2pi i k1 n2/640}
//   TW40P  @ 1008 ( 40)  [m2*8+j1]  = e^{+2pi i j1 m2/40}
//   F23P   @ 1048 (253)  [k2*11+m-1]= (cos,sin)(2pi k2 m/23)
// ---------------------------------------------------------------------------
__global__ void init_tables_kernel(float2* __restrict__ T){
    int i = blockIdx.x*blockDim.x + threadIdx.x;
    if (i >= 1301) return;
    int r, c, modN; int j;
    if      (i <  368){ j = i;        r = j%16; c = j/16; modN = 368; }
    else if (i < 1008){ j = i-368;    r = j%16; c = j/16; modN = 640; }
    else if (i < 1048){ j = i-1008;   r = j%8;  c = j/8;  modN = 40;  }
    else              { j = i-1048;   r = j/11; c = j%11 + 1; modN = 23; }
    int t = (int)(((long long)r * c) % modN);
    if (t > modN/2) t -= modN;
    float ang = (float)(6.283185307179586 * ((double)t / (double)modN));
    float s, co;
    sincosf(ang, &s, &co);
    T[i] = make_float2(co, s);
}

// ---------------------------------------------------------------------------
// K1 (MFMA, round-8 v1 revert): fused k-branch. One block per (b,h) row.
// Raw-row staging (coalesced), scalar u16 frag builds (48 us known-good;
// round-9's per-k im2col staging was latency-bound at 55 us).
// ---------------------------------------------------------------------------
__global__ __launch_bounds__(256) void kbranch_mfma(const float* __restrict__ ksp,
                               const float* __restrict__ wk,
                               const float* __restrict__ bk,
                               const float* __restrict__ w1,
                               const float* __restrict__ b1,
                               float2* __restrict__ A){
    __shared__ unsigned short Sb[2616];     // 6x372 bf16 tile + zero pad region
    __shared__ unsigned short Wr[4*512];    // per-wave 16px x 32oc transpose buf
    int t = threadIdx.x;
    int bh = blockIdx.x;                    // b*640 + h
    int h = bh % 640, b = bh / 640;

    // stage input rows (h-1,h,h+1) x 2ch as bf16, halo col +1, zeros elsewhere
    for (int i = t; i < 2616; i += 256){
        float val = 0.f;
        if (i < 2232){
            int rr = i / 372, col = i - rr*372;
            int r = rr >> 1, ic = rr & 1;
            int hh = h - 1 + r, sc = col - 1;
            if ((unsigned)hh < 640u && (unsigned)sc < 368u)
                val = ksp[((b*2 + ic)*640 + hh)*368 + sc];
        }
        Sb[i] = f2bf(val);
    }

    int lane = t & 63, wave = t >> 6;
    int oc = lane & 15, q = lane >> 4;      // oc: col idx; q: quad
    int off[8];
    v8s bf0, bf1, b2f;
    #pragma unroll
    for (int j = 0; j < 8; ++j){
        int kk = q*8 + j;
        if (kk < 18){
            int ic = (kk >= 9) ? 1 : 0;
            int tt = kk - ic*9;
            int ty = tt/3, tx = tt - ty*3;
            off[j] = (ty*2 + ic)*372 + tx;
            bf0[j] = (short)f2bf(wk[oc*18 + kk]);
            bf1[j] = (short)f2bf(wk[(oc+16)*18 + kk]);
        } else {
            off[j] = 2232;                  // zeroed region (addr+px < 2616)
            bf0[j] = 0; bf1[j] = 0;
        }
        b2f[j] = (oc < 2) ? (short)f2bf(w1[oc*32 + kk]) : (short)0;
    }
    float bk0 = bk[oc], bk1 = bk[oc+16];
    float biasn = (oc == 1) ? b1[1] : b1[0];
    unsigned short* Wrw = Wr + (wave << 9);
    __syncthreads();

    int gbase = wave*6;
    int cnt = (wave < 3) ? 6 : 5;           // 23 groups of 16 px
    for (int i = 0; i < cnt; ++i){
        int g = gbase + i;
        int w0m = g*16 + oc;                // pixel m for this lane
        v8s af;
        #pragma unroll
        for (int j = 0; j < 8; ++j) af[j] = (short)Sb[off[j] + w0m];
        v4f d0 = {0.f,0.f,0.f,0.f}, d1 = {0.f,0.f,0.f,0.f};
        d0 = __builtin_amdgcn_mfma_f32_16x16x32_bf16(af, bf0, d0, 0, 0, 0);
        d1 = __builtin_amdgcn_mfma_f32_16x16x32_bf16(af, bf1, d1, 0, 0, 0);
        // bias + leaky, transpose (oc-major -> px-major) via wave-local LDS
        #pragma unroll
        for (int r = 0; r < 4; ++r){
            int px = q*4 + r;
            Wrw[px*32 + oc]      = f2bf(leaky_(d0[r] + bk0));
            Wrw[px*32 + 16 + oc] = f2bf(leaky_(d1[r] + bk1));
        }
        asm volatile("s_waitcnt lgkmcnt(0)" ::: "memory");
        const v8s* ap = (const v8s*)(Wrw + oc*32);   // m = lane&15, 16B aligned
        v8s a2 = ap[q];                              // k-slice = q*8..q*8+7
        v4f d2 = {0.f,0.f,0.f,0.f};
        d2 = __builtin_amdgcn_mfma_f32_16x16x32_bf16(a2, b2f, d2, 0, 0, 0);
        float vals[4], ov[4];
        #pragma unroll
        for (int r = 0; r < 4; ++r){
            vals[r] = leaky_(biasn + d2[r]);
            ov[r] = __shfl_xor(vals[r], 1);          // col1 (o1) -> col-0 lane
        }
        if (oc == 0){
            float2* dst = A + (size_t)bh*368 + g*16 + q*4;
            *(float4*)dst       = make_float4(vals[0], ov[0], vals[1], ov[1]);
            *(float4*)(dst + 2) = make_float4(vals[2], ov[2], vals[3], ov[3]);
        }
        asm volatile("s_waitcnt lgkmcnt(0)" ::: "memory");  // Wr reuse fence
    }
}

// ---------------------------------------------------------------------------
// K2: W-axis centered IFFT, W = 368 = 16*23.  8 lines/block, 640 blocks.
// NEW: output written TRANSPOSED to Bt[b][w][h] (64B segments from LDS) so
// the H-pass can run fully coalesced line-major.
// ---------------------------------------------------------------------------
__global__ __launch_bounds__(256) void fftW_kernel(const float2* __restrict__ A,
                                                   const float2* __restrict__ TW368P,
                                                   const float2* __restrict__ F23P,
                                                   float2* __restrict__ Bt){
    __shared__ float2 X[WLINES*369];      // 23,616 B
    int t = threadIdx.x;
    size_t base = (size_t)blockIdx.x * (WLINES*368);

    for (int i = t; i < WLINES*368; i += 256){
        int l = i / 368, n = i - l*368;
        float2 v = A[base + i];
        float s = (n & 1) ? -1.f : 1.f;            // (-1)^n
        X[l*369 + n] = make_float2(v.x*s, v.y*s);
    }
    __syncthreads();

    // stage 1: items (l,n2) = 184
    if (t < 184){
        int l = t & 7, n2 = t >> 3;
        float2 xr[16], Xo[16];
        #pragma unroll
        for (int n1 = 0; n1 < 16; ++n1) xr[n1] = X[l*369 + 23*n1 + n2];
        fft16p_(xr, Xo);
        const float2* row = TW368P + n2*16;
        #pragma unroll
        for (int k1 = 0; k1 < 16; ++k1)
            X[l*369 + 23*k1 + n2] = cmulv_(Xo[k1], row[k1]);
    }
    __syncthreads();

    // stage 2: DFT23 via pairs; 256 units = (l,k1,half)
    {
        int l = t & 7, k1 = (t >> 3) & 15, half = t >> 7;
        const float2* xp = X + l*369 + 23*k1;
        float2 x0 = xp[0];
        float2 u[11], d[11];
        #pragma unroll
        for (int m = 1; m <= 11; ++m){
            float2 a = xp[m], bb = xp[23-m];
            u[m-1] = cadd_(a, bb);
            d[m-1] = csub_(a, bb);
        }
        __syncthreads();
        int k2beg = half ? 12 : 0;
        int k2end = half ? 23 : 12;
        for (int k2 = k2beg; k2 < k2end; ++k2){
            const float2* row = F23P + k2*11;      // wave-uniform -> s_load
            float re = x0.x, im = x0.y;
            #pragma unroll
            for (int m = 0; m < 11; ++m){
                float c = row[m].x, s = row[m].y;
                re += u[m].x*c - d[m].y*s;
                im += u[m].y*c + d[m].x*s;
            }
            X[l*369 + k1 + 16*k2] = make_float2(re, im);
        }
    }
    __syncthreads();

    // transposed store: Bt[(b*368 + k)*640 + h0 + l], 8-float2 (64B) segments
    const float sc = 0.052129458158616354f;        // 1/sqrt(368)
    int b  = blockIdx.x / 80;
    int h0 = (blockIdx.x - b*80) * WLINES;
    for (int i = t; i < WLINES*368; i += 256){
        int k = i >> 3, l = i & 7;
        float2 v = X[l*369 + k];
        float s = (k & 1) ? -sc : sc;              // (-1)^k
        Bt[((size_t)(b*368 + k))*640 + h0 + l] = make_float2(v.x*s, v.y*s);
    }
}

// ---------------------------------------------------------------------------
// K3: H-axis centered IFFT, H = 640 = 16*8*5.  Line-major: block = 4 (b,w)
// lines of 640 contiguous samples from Bt; output A2[b][w][h] contiguous.
// Fully coalesced global IO (512B/wave).  736 blocks.
// ---------------------------------------------------------------------------
__global__ __launch_bounds__(256) void fftH_kernel(const float2* __restrict__ Bt,
                                                   const float2* __restrict__ TW640P,
                                                   const float2* __restrict__ TW40P,
                                                   float2* __restrict__ A2){
    __shared__ float2 X[HLINES*HP];       // 20,640 B
    int t = threadIdx.x;
    size_t base = (size_t)blockIdx.x * (HLINES*640);

    for (int i = t; i < HLINES*640; i += 256){
        int l = i / 640, n = i - l*640;
        float2 v = Bt[base + i];
        float s = (n & 1) ? -1.f : 1.f;            // (-1)^n
        X[l*HP + n] = make_float2(v.x*s, v.y*s);
    }
    __syncthreads();

    // stage 1: FFT16 over n1, items (l,n2) = 160
    if (t < 160){
        int l = t & 3, n2 = t >> 2;
        float2 xr[16], Xo[16];
        #pragma unroll
        for (int n1 = 0; n1 < 16; ++n1) xr[n1] = X[l*HP + 40*n1 + n2];
        fft16p_(xr, Xo);
        const float2* row = TW640P + n2*16;
        #pragma unroll
        for (int k1 = 0; k1 < 16; ++k1)
            X[l*HP + 40*k1 + n2] = cmulv_(Xo[k1], row[k1]);
    }
    __syncthreads();

    // stage 2a: FFT8 over m1, items (l,k1,m2) = 320
    for (int it = t; it < 320; it += 256){
        int l = it & 3, k1 = (it >> 2) & 15, m2 = it >> 6;
        float2 xr[8], Xo[8];
        #pragma unroll
        for (int m1 = 0; m1 < 8; ++m1) xr[m1] = X[l*HP + 40*k1 + 5*m1 + m2];
        fft8p_(xr, Xo);
        const float2* row = TW40P + m2*8;
        #pragma unroll
        for (int j1 = 0; j1 < 8; ++j1)
            X[l*HP + 40*k1 + 5*j1 + m2] = cmulv_(Xo[j1], row[j1]);
    }
    __syncthreads();

    // stage 2b: DFT5 over m2 via pairs, items (l,k1,j1) = 512 -> 2/thread
    {
        const float CK1[5] = {1.f,  0.30901699437494745f, -0.8090169943749475f, -0.8090169943749475f,  0.30901699437494745f};
        const float SK1[5] = {0.f,  0.9510565162951535f,   0.5877852522924731f, -0.5877852522924731f, -0.9510565162951535f};
        const float CK2[5] = {1.f, -0.8090169943749475f,   0.30901699437494745f, 0.30901699437494745f, -0.8090169943749475f};
        const float SK2[5] = {0.f,  0.5877852522924731f,  -0.9510565162951535f,  0.9510565162951535f, -0.5877852522924731f};
        int it0 = t, it1 = t + 256;
        int l0 = it0 & 3, k10 = (it0 >> 2) & 15, j10 = it0 >> 6;
        int l1 = it1 & 3, k11 = (it1 >> 2) & 15, j11 = it1 >> 6;
        float2 p0[5], p1[5];
        #pragma unroll
        for (int m2 = 0; m2 < 5; ++m2) p0[m2] = X[l0*HP + 40*k10 + 5*j10 + m2];
        #pragma unroll
        for (int m2 = 0; m2 < 5; ++m2) p1[m2] = X[l1*HP + 40*k11 + 5*j11 + m2];
        __syncthreads();
        float2 u0a = cadd_(p0[1], p0[4]), d0a = csub_(p0[1], p0[4]);
        float2 u0b = cadd_(p0[2], p0[3]), d0b = csub_(p0[2], p0[3]);
        float2 u1a = cadd_(p1[1], p1[4]), d1a = csub_(p1[1], p1[4]);
        float2 u1b = cadd_(p1[2], p1[3]), d1b = csub_(p1[2], p1[3]);
        #pragma unroll
        for (int j2 = 0; j2 < 5; ++j2){
            float c1v = CK1[j2], s1v = SK1[j2], c2v = CK2[j2], s2v = SK2[j2];
            float re0 = p0[0].x + u0a.x*c1v - d0a.y*s1v + u0b.x*c2v - d0b.y*s2v;
            float im0 = p0[0].y + u0a.y*c1v + d0a.x*s1v + u0b.y*c2v + d0b.x*s2v;
            float re1 = p1[0].x + u1a.x*c1v - d1a.y*s1v + u1b.x*c2v - d1b.y*s2v;
            float im1 = p1[0].y + u1a.y*c1v + d1a.x*s1v + u1b.y*c2v + d1b.x*s2v;
            X[l0*HP + k10 + 16*j10 + 128*j2] = make_float2(re0, im0);
            X[l1*HP + k11 + 16*j11 + 128*j2] = make_float2(re1, im1);
        }
    }
    __syncthreads();

    const float sc = 0.03952847075210474f;         // 1/sqrt(640)
    for (int i = t; i < HLINES*640; i += 256){
        int l = i / 640, k = i - l*640;
        float2 v = X[l*HP + k];
        float s = (k & 1) ? -sc : sc;              // (-1)^k
        A2[base + i] = make_float2(v.x*s, v.y*s);
    }
}

// ---------------------------------------------------------------------------
// K4 (fused tail): B-axis FFT8 + magnitude + fp16-emulated conv2(1x1) + leaky
//                  + conv3x3(1->1, pad1) + leaky -> d_out.
// A2 is transposed [b][w][h]: pass 1a reads it h-coalesced (mag into Pl);
// pass 1b reads img w-coalesced and applies conv2; stage 2 conv from LDS.
// ---------------------------------------------------------------------------
__global__ __launch_bounds__(256) void tail_kernel(const float2* __restrict__ A2,
                                  const float* __restrict__ img,
                                  const float* __restrict__ w2,
                                  const float* __restrict__ b2,
                                  const float* __restrict__ wi,
                                  const float* __restrict__ bi,
                                  float* __restrict__ out){
    __shared__ float Pl[8][TS+2][TS+3];            // pitch 19: 2-way banks
    int t = threadIdx.x;
    int ty0 = (blockIdx.x / 23) * TS;              // 40 tiles over h
    int tx0 = (blockIdx.x % 23) * TS;              // 23 tiles over w

    float w2h0 = __half2float(__float2half(w2[0]));
    float w2h1 = __half2float(__float2half(w2[1]));
    float b2h  = __half2float(__float2half(b2[0]));
    const float sc8 = 0.35355339059327373f;        // 1/sqrt(8)

    // pass 1a: |centered ifft8| from A2, lanes sweep h (coalesced 144B runs)
    for (int idx = t; idx < (TS+2)*(TS+2); idx += 256){
        int hx = idx / (TS+2), hy = idx - hx*(TS+2);
        int hh = ty0 - 1 + hy, ww = tx0 - 1 + hx;
        int hc = min(max(hh, 0), H_-1), wc = min(max(ww, 0), W_-1);
        float2 x[8], Xo[8];
        #pragma unroll
        for (int n = 0; n < 8; ++n){
            float2 v = A2[((size_t)(n*368 + wc))*640 + hc];
            float s = (n & 1) ? -1.f : 1.f;        // (-1)^n
            x[n] = make_float2(v.x*s, v.y*s);
        }
        fft8p_(x, Xo);
        #pragma unroll
        for (int k = 0; k < 8; ++k){
            float s = (k & 1) ? -sc8 : sc8;        // (-1)^k / sqrt(8)
            float yr = Xo[k].x * s, yi = Xo[k].y * s;
            float mag = sqrtf(yr*yr + yi*yi);
            Pl[k][hy][hx] = __half2float(__float2half(mag));
        }
    }
    __syncthreads();

    // pass 1b: conv2 with img, lanes sweep w (coalesced img reads)
    for (int idx = t; idx < (TS+2)*(TS+2); idx += 256){
        int hy = idx / (TS+2), hx = idx - hy*(TS+2);
        int hh = ty0 - 1 + hy, ww = tx0 - 1 + hx;
        bool inb = (hh >= 0) && (hh < H_) && (ww >= 0) && (ww < W_);
        int hc = min(max(hh, 0), H_-1), wc = min(max(ww, 0), W_-1);
        float inbf = inb ? 1.f : 0.f;
        #pragma unroll
        for (int k = 0; k < 8; ++k){
            float g = __half2float(__float2half(img[(size_t)k*HW_ + hc*W_ + wc]));
            float a = Pl[k][hy][hx];
            float o = leaky_(a*w2h0 + g*w2h1 + b2h);
            o = __half2float(__float2half(o));
            Pl[k][hy][hx] = o * inbf;              // zero-pad outside image
        }
    }
    __syncthreads();

    // stage 2: conv3x3 from LDS, 256 spatial px x 8 batch per block
    int sy = t >> 4, sx = t & 15;
    float wv[9];
    #pragma unroll
    for (int q = 0; q < 9; ++q) wv[q] = wi[q];
    float bi0 = bi[0];
    #pragma unroll
    for (int k = 0; k < 8; ++k){
        float acc = bi0;
        #pragma unroll
        for (int dy = 0; dy < 3; ++dy)
            #pragma unroll
            for (int dx = 0; dx < 3; ++dx)
                acc += wv[dy*3+dx] * Pl[k][sy+dy][sx+dx];
        out[((size_t)k*H_ + ty0+sy)*W_ + tx0+sx] = leaky_(acc);
    }
}

// ---------------------------------------------------------------------------
// Workspace layout (bytes):
//   A/A2   : float2[NP]    @ 0            (15,073,280)   A=[b][h][w], A2=[b][w][h]
//   Bt     : float2[NP]    @ 15,073,280   (15,073,280)   [b][w][h]
//   tables : float2[1301]  @ 30,146,560   (10,408)
// ---------------------------------------------------------------------------
extern "C" void kernel_launch(void* const* d_in, const int* in_sizes, int n_in,
                              void* d_out, int out_size, void* d_ws, size_t ws_size,
                              hipStream_t stream){
    const float* img = (const float*)d_in[0];
    const float* ksp = (const float*)d_in[1];
    const float* wk  = (const float*)d_in[2];
    const float* bk  = (const float*)d_in[3];
    const float* w1  = (const float*)d_in[4];
    const float* b1  = (const float*)d_in[5];
    const float* w2  = (const float*)d_in[6];
    const float* b2  = (const float*)d_in[7];
    const float* wi  = (const float*)d_in[8];
    const float* bi  = (const float*)d_in[9];

    char* ws = (char*)d_ws;
    float2* A   = (float2*)(ws + 0);
    float2* Bt  = (float2*)(ws + 15073280);
    float2* T   = (float2*)(ws + 30146560);
    float2* TW368P = T + 0;
    float2* TW640P = T + 368;
    float2* TW40P  = T + 1008;
    float2* F23P   = T + 1048;
    float* out  = (float*)d_out;

    init_tables_kernel<<<6, 256, 0, stream>>>(T);

    kbranch_mfma<<<B_*H_, 256, 0, stream>>>(ksp, wk, bk, w1, b1, A);

    fftW_kernel<<<(B_*H_)/WLINES, 256, 0, stream>>>(A, TW368P, F23P, Bt);     // A -> Bt (transposed)
    fftH_kernel<<<(B_*W_)/HLINES, 256, 0, stream>>>(Bt, TW640P, TW40P, A);    // Bt -> A2 (in A region)

    tail_kernel<<<(H_/TS)*(W_/TS), 256, 0, stream>>>(A, img, w2, b2, wi, bi, out);
}

// Round 11
// 172.437 us; speedup vs baseline: 1.0064x; 1.0018x over previous
//
#include <hip/hip_runtime.h>
#include <hip/hip_fp16.h>
#include <math.h>

// Problem dims
#define B_ 8
#define H_ 640
#define W_ 368
#define HW_ (H_*W_)
#define NP_ (B_*H_*W_)   // 1,884,160

#define FROWS 4          // h-rows per block in fused kbranch+fftW kernel
#define HLINES 4         // (b,w) lines per block in H-axis FFT
#define HP 645           // LDS pitch (float2) for H kernel
#define TS 16            // spatial tile for fused tail kernel

typedef __attribute__((ext_vector_type(8))) short v8s;   // 8 bf16 (4 VGPR)
typedef __attribute__((ext_vector_type(4))) float v4f;   // MFMA acc

__device__ __forceinline__ float leaky_(float x){ return fmaxf(x, 0.01f*x); }

// fp32 -> bf16 round-to-nearest-even
__device__ __forceinline__ unsigned short f2bf(float x){
    unsigned u = __float_as_uint(x);
    u += 0x7FFFu + ((u >> 16) & 1u);
    return (unsigned short)(u >> 16);
}

__device__ __forceinline__ float2 cadd_(float2 a, float2 b){ return make_float2(a.x+b.x, a.y+b.y); }
__device__ __forceinline__ float2 csub_(float2 a, float2 b){ return make_float2(a.x-b.x, a.y-b.y); }
__device__ __forceinline__ float2 cmul_(float2 a, float c, float s){
    return make_float2(a.x*c - a.y*s, a.x*s + a.y*c);
}
__device__ __forceinline__ float2 cmulv_(float2 a, float2 w){
    return make_float2(a.x*w.x - a.y*w.y, a.x*w.y + a.y*w.x);
}

// DFT4 with +i convention
__device__ __forceinline__ void dft4p_(float2 p0, float2 p1, float2 p2, float2 p3,
                                       float2& z0, float2& z1, float2& z2, float2& z3){
    float2 s0 = cadd_(p0,p2), d0 = csub_(p0,p2);
    float2 s1 = cadd_(p1,p3), d1 = csub_(p1,p3);
    z0 = cadd_(s0,s1);
    z2 = csub_(s0,s1);
    z1 = make_float2(d0.x - d1.y, d0.y + d1.x);
    z3 = make_float2(d0.x + d1.y, d0.y - d1.x);
}

// 16-point DFT, +i convention
__device__ __forceinline__ void fft16p_(const float2* x, float2* X){
    const float C1 = 0.9238795325112867f, S1 = 0.3826834323650898f;
    const float R  = 0.7071067811865476f;
    float2 Y[4][4];
    #pragma unroll
    for (int b = 0; b < 4; ++b)
        dft4p_(x[b], x[4+b], x[8+b], x[12+b], Y[b][0], Y[b][1], Y[b][2], Y[b][3]);
    Y[1][1] = cmul_(Y[1][1],  C1,  S1);
    Y[1][2] = cmul_(Y[1][2],   R,   R);
    Y[1][3] = cmul_(Y[1][3],  S1,  C1);
    Y[2][1] = cmul_(Y[2][1],   R,   R);
    Y[2][2] = make_float2(-Y[2][2].y, Y[2][2].x);
    Y[2][3] = cmul_(Y[2][3],  -R,   R);
    Y[3][1] = cmul_(Y[3][1],  S1,  C1);
    Y[3][2] = cmul_(Y[3][2],  -R,   R);
    Y[3][3] = cmul_(Y[3][3], -C1, -S1);
    #pragma unroll
    for (int c = 0; c < 4; ++c)
        dft4p_(Y[0][c], Y[1][c], Y[2][c], Y[3][c], X[c], X[c+4], X[c+8], X[c+12]);
}

// 8-point DFT, +i convention
__device__ __forceinline__ void fft8p_(const float2* x, float2* X){
    const float R = 0.7071067811865476f;
    float2 Y0[4], Y1[4];
    dft4p_(x[0], x[2], x[4], x[6], Y0[0], Y0[1], Y0[2], Y0[3]);
    dft4p_(x[1], x[3], x[5], x[7], Y1[0], Y1[1], Y1[2], Y1[3]);
    float2 T0 = Y1[0];
    float2 T1 = cmul_(Y1[1],  R, R);
    float2 T2 = make_float2(-Y1[2].y, Y1[2].x);
    float2 T3 = cmul_(Y1[3], -R, R);
    X[0] = cadd_(Y0[0], T0);  X[4] = csub_(Y0[0], T0);
    X[1] = cadd_(Y0[1], T1);  X[5] = csub_(Y0[1], T1);
    X[2] = cadd_(Y0[2], T2);  X[6] = csub_(Y0[2], T2);
    X[3] = cadd_(Y0[3], T3);  X[7] = csub_(Y0[3], T3);
}

// ---------------------------------------------------------------------------
// Tables (float2 indices in T):
//   TW368P @    0 (368)  [n2*16+k1] = e^{+2pi i k1 n2/368}
//   TW640P @  368 (640)  [n2*16+k1] = e^{+2pi i k1 n2/640}
//   TW40P  @ 1008 ( 40)  [m2*8+j1]  = e^{+2pi i j1 m2/40}
//   F23P   @ 1048 (253)  [k2*11+m-1]= (cos,sin)(2pi k2 m/23)
// ---------------------------------------------------------------------------
__global__ void init_tables_kernel(float2* __restrict__ T){
    int i = blockIdx.x*blockDim.x + threadIdx.x;
    if (i >= 1301) return;
    int r, c, modN; int j;
    if      (i <  368){ j = i;        r = j%16; c = j/16; modN = 368; }
    else if (i < 1008){ j = i-368;    r = j%16; c = j/16; modN = 640; }
    else if (i < 1048){ j = i-1008;   r = j%8;  c = j/8;  modN = 40;  }
    else              { j = i-1048;   r = j/11; c = j%11 + 1; modN = 23; }
    int t = (int)(((long long)r * c) % modN);
    if (t > modN/2) t -= modN;
    float ang = (float)(6.283185307179586 * ((double)t / (double)modN));
    float s, co;
    sincosf(ang, &s, &co);
    T[i] = make_float2(co, s);
}

// ---------------------------------------------------------------------------
// K1 (fused kbranch + W-FFT): block = 4 consecutive h rows of one b.
//  Phase 1: stage 6 input rows x 2ch as bf16 (coalesced), zero pad region.
//  Phase 2: MFMA conv3x3(2->32)+leaky -> LDS transpose -> MFMA 1x1(32->2)
//           +leaky; results written straight into fft buffer X with the
//           (-1)^n centering sign folded in (no global A round-trip).
//  Phase 3: W-FFT (368 = 16*23) on the 4 in-LDS lines; store Bt transposed.
// ---------------------------------------------------------------------------
__global__ __launch_bounds__(256) void kfftw_kernel(const float* __restrict__ ksp,
                               const float* __restrict__ wk,
                               const float* __restrict__ bk,
                               const float* __restrict__ w1,
                               const float* __restrict__ b1,
                               const float2* __restrict__ TW368P,
                               const float2* __restrict__ F23P,
                               float2* __restrict__ Bt){
    __shared__ unsigned short Sb[4836];     // 6 rows x 2ch x 372 + zero region
    __shared__ unsigned short Wr[4*512];    // per-wave 16px x 32oc transpose buf
    __shared__ float2 X[FROWS*369];         // fft working set (11,808 B)
    int t = threadIdx.x;
    int blk = blockIdx.x;                   // b*160 + h0/4
    int b  = blk / 160;
    int h0 = (blk - b*160) * FROWS;

    // Phase 1: stage rows h0-1 .. h0+4, both channels, halo col +1
    for (int seg = 0; seg < 12; ++seg){
        int r = seg >> 1, ic = seg & 1;
        int hh = h0 - 1 + r;
        int ok = ((unsigned)hh < 640u);
        const float* base = ksp + ((size_t)(b*2 + ic)*640 + (ok ? hh : 0))*368;
        for (int col = t; col < 372; col += 256){
            int c = col - 1;
            float v = (ok && (unsigned)c < 368u) ? base[c] : 0.f;
            Sb[seg*372 + col] = f2bf(v);
        }
    }
    for (int i = t; i < 372; i += 256) Sb[4464 + i] = 0;   // zero pad for k>=18

    int lane = t & 63, wave = t >> 6;
    int oc = lane & 15, q = lane >> 4;
    int l = wave;                           // wave owns row h0+l

    int off[8];
    v8s bf0, bf1, b2f;
    #pragma unroll
    for (int j = 0; j < 8; ++j){
        int kk = q*8 + j;
        if (kk < 18){
            int ic = (kk >= 9) ? 1 : 0;
            int tt = kk - ic*9;
            int ty = tt/3, tx = tt - ty*3;
            off[j] = ((ty + l)*2 + ic)*372 + tx;
            bf0[j] = (short)f2bf(wk[oc*18 + kk]);
            bf1[j] = (short)f2bf(wk[(oc+16)*18 + kk]);
        } else {
            off[j] = 4464;                  // zeroed region
            bf0[j] = 0; bf1[j] = 0;
        }
        b2f[j] = (oc < 2) ? (short)f2bf(w1[oc*32 + kk]) : (short)0;
    }
    float bk0 = bk[oc], bk1 = bk[oc+16];
    float biasn = (oc == 1) ? b1[1] : b1[0];
    unsigned short* Wrw = Wr + (wave << 9);
    __syncthreads();

    // Phase 2: 23 groups of 16 px per wave (row l)
    for (int g = 0; g < 23; ++g){
        int w0m = g*16 + oc;
        v8s af;
        #pragma unroll
        for (int j = 0; j < 8; ++j) af[j] = (short)Sb[off[j] + w0m];
        v4f d0 = {0.f,0.f,0.f,0.f}, d1 = {0.f,0.f,0.f,0.f};
        d0 = __builtin_amdgcn_mfma_f32_16x16x32_bf16(af, bf0, d0, 0, 0, 0);
        d1 = __builtin_amdgcn_mfma_f32_16x16x32_bf16(af, bf1, d1, 0, 0, 0);
        #pragma unroll
        for (int r = 0; r < 4; ++r){
            int px = q*4 + r;
            Wrw[px*32 + oc]      = f2bf(leaky_(d0[r] + bk0));
            Wrw[px*32 + 16 + oc] = f2bf(leaky_(d1[r] + bk1));
        }
        asm volatile("s_waitcnt lgkmcnt(0)" ::: "memory");
        const v8s* ap = (const v8s*)(Wrw + oc*32);
        v8s a2 = ap[q];
        v4f d2 = {0.f,0.f,0.f,0.f};
        d2 = __builtin_amdgcn_mfma_f32_16x16x32_bf16(a2, b2f, d2, 0, 0, 0);
        float vals[4], ov[4];
        #pragma unroll
        for (int r = 0; r < 4; ++r){
            vals[r] = leaky_(biasn + d2[r]);
            ov[r] = __shfl_xor(vals[r], 1);          // o1 (col 1) -> col-0 lane
        }
        if (oc == 0){
            int px = g*16 + q*4;                     // even -> signs +,-,+,-
            X[l*369 + px  ] = make_float2( vals[0],  ov[0]);
            X[l*369 + px+1] = make_float2(-vals[1], -ov[1]);
            X[l*369 + px+2] = make_float2( vals[2],  ov[2]);
            X[l*369 + px+3] = make_float2(-vals[3], -ov[3]);
        }
        asm volatile("s_waitcnt lgkmcnt(0)" ::: "memory");  // Wr reuse fence
    }
    __syncthreads();

    // Phase 3a: FFT16 over n1, items (l,n2) = 92
    if (t < 92){
        int ll = t & 3, n2 = t >> 2;
        float2 xr[16], Xo[16];
        #pragma unroll
        for (int n1 = 0; n1 < 16; ++n1) xr[n1] = X[ll*369 + 23*n1 + n2];
        fft16p_(xr, Xo);
        const float2* row = TW368P + n2*16;
        #pragma unroll
        for (int k1 = 0; k1 < 16; ++k1)
            X[ll*369 + 23*k1 + n2] = cmulv_(Xo[k1], row[k1]);
    }
    __syncthreads();

    // Phase 3b: DFT23 via pairs; 256 units = (l,k1,quarter)
    {
        int ll = t & 3, k1 = (t >> 2) & 15, qr = t >> 6;   // qr wave-uniform
        const float2* xp = X + ll*369 + 23*k1;
        float2 x0 = xp[0];
        float2 u[11], d[11];
        #pragma unroll
        for (int m = 1; m <= 11; ++m){
            float2 a = xp[m], bb = xp[23-m];
            u[m-1] = cadd_(a, bb);
            d[m-1] = csub_(a, bb);
        }
        __syncthreads();
        int k2beg = qr*6;
        int k2end = (qr == 3) ? 23 : k2beg + 6;
        for (int k2 = k2beg; k2 < k2end; ++k2){
            const float2* row = F23P + k2*11;      // wave-uniform -> s_load
            float re = x0.x, im = x0.y;
            #pragma unroll
            for (int m = 0; m < 11; ++m){
                float c = row[m].x, s = row[m].y;
                re += u[m].x*c - d[m].y*s;
                im += u[m].y*c + d[m].x*s;
            }
            X[ll*369 + k1 + 16*k2] = make_float2(re, im);
        }
    }
    __syncthreads();

    // Phase 3c: transposed store Bt[(b*368+k)*640 + h0 + l]
    const float sc = 0.052129458158616354f;        // 1/sqrt(368)
    for (int i = t; i < FROWS*368; i += 256){
        int k = i >> 2, ll = i & 3;
        float2 v = X[ll*369 + k];
        float s = (k & 1) ? -sc : sc;              // (-1)^k
        Bt[((size_t)(b*368 + k))*640 + h0 + ll] = make_float2(v.x*s, v.y*s);
    }
}

// ---------------------------------------------------------------------------
// K2: H-axis centered IFFT, H = 640 = 16*8*5.  Line-major over Bt[b][w][h];
// output A2[b][w][h] contiguous. Fully coalesced global IO.  736 blocks.
// ---------------------------------------------------------------------------
__global__ __launch_bounds__(256) void fftH_kernel(const float2* __restrict__ Bt,
                                                   const float2* __restrict__ TW640P,
                                                   const float2* __restrict__ TW40P,
                                                   float2* __restrict__ A2){
    __shared__ float2 X[HLINES*HP];       // 20,640 B
    int t = threadIdx.x;
    size_t base = (size_t)blockIdx.x * (HLINES*640);

    for (int i = t; i < HLINES*640; i += 256){
        int l = i / 640, n = i - l*640;
        float2 v = Bt[base + i];
        float s = (n & 1) ? -1.f : 1.f;            // (-1)^n
        X[l*HP + n] = make_float2(v.x*s, v.y*s);
    }
    __syncthreads();

    // stage 1: FFT16 over n1, items (l,n2) = 160
    if (t < 160){
        int l = t & 3, n2 = t >> 2;
        float2 xr[16], Xo[16];
        #pragma unroll
        for (int n1 = 0; n1 < 16; ++n1) xr[n1] = X[l*HP + 40*n1 + n2];
        fft16p_(xr, Xo);
        const float2* row = TW640P + n2*16;
        #pragma unroll
        for (int k1 = 0; k1 < 16; ++k1)
            X[l*HP + 40*k1 + n2] = cmulv_(Xo[k1], row[k1]);
    }
    __syncthreads();

    // stage 2a: FFT8 over m1, items (l,k1,m2) = 320
    for (int it = t; it < 320; it += 256){
        int l = it & 3, k1 = (it >> 2) & 15, m2 = it >> 6;
        float2 xr[8], Xo[8];
        #pragma unroll
        for (int m1 = 0; m1 < 8; ++m1) xr[m1] = X[l*HP + 40*k1 + 5*m1 + m2];
        fft8p_(xr, Xo);
        const float2* row = TW40P + m2*8;
        #pragma unroll
        for (int j1 = 0; j1 < 8; ++j1)
            X[l*HP + 40*k1 + 5*j1 + m2] = cmulv_(Xo[j1], row[j1]);
    }
    __syncthreads();

    // stage 2b: DFT5 over m2 via pairs, items (l,k1,j1) = 512 -> 2/thread
    {
        const float CK1[5] = {1.f,  0.30901699437494745f, -0.8090169943749475f, -0.8090169943749475f,  0.30901699437494745f};
        const float SK1[5] = {0.f,  0.9510565162951535f,   0.5877852522924731f, -0.5877852522924731f, -0.9510565162951535f};
        const float CK2[5] = {1.f, -0.8090169943749475f,   0.30901699437494745f, 0.30901699437494745f, -0.8090169943749475f};
        const float SK2[5] = {0.f,  0.5877852522924731f,  -0.9510565162951535f,  0.9510565162951535f, -0.5877852522924731f};
        int it0 = t, it1 = t + 256;
        int l0 = it0 & 3, k10 = (it0 >> 2) & 15, j10 = it0 >> 6;
        int l1 = it1 & 3, k11 = (it1 >> 2) & 15, j11 = it1 >> 6;
        float2 p0[5], p1[5];
        #pragma unroll
        for (int m2 = 0; m2 < 5; ++m2) p0[m2] = X[l0*HP + 40*k10 + 5*j10 + m2];
        #pragma unroll
        for (int m2 = 0; m2 < 5; ++m2) p1[m2] = X[l1*HP + 40*k11 + 5*j11 + m2];
        __syncthreads();
        float2 u0a = cadd_(p0[1], p0[4]), d0a = csub_(p0[1], p0[4]);
        float2 u0b = cadd_(p0[2], p0[3]), d0b = csub_(p0[2], p0[3]);
        float2 u1a = cadd_(p1[1], p1[4]), d1a = csub_(p1[1], p1[4]);
        float2 u1b = cadd_(p1[2], p1[3]), d1b = csub_(p1[2], p1[3]);
        #pragma unroll
        for (int j2 = 0; j2 < 5; ++j2){
            float c1v = CK1[j2], s1v = SK1[j2], c2v = CK2[j2], s2v = SK2[j2];
            float re0 = p0[0].x + u0a.x*c1v - d0a.y*s1v + u0b.x*c2v - d0b.y*s2v;
            float im0 = p0[0].y + u0a.y*c1v + d0a.x*s1v + u0b.y*c2v + d0b.x*s2v;
            float re1 = p1[0].x + u1a.x*c1v - d1a.y*s1v + u1b.x*c2v - d1b.y*s2v;
            float im1 = p1[0].y + u1a.y*c1v + d1a.x*s1v + u1b.y*c2v + d1b.x*s2v;
            X[l0*HP + k10 + 16*j10 + 128*j2] = make_float2(re0, im0);
            X[l1*HP + k11 + 16*j11 + 128*j2] = make_float2(re1, im1);
        }
    }
    __syncthreads();

    const float sc = 0.03952847075210474f;         // 1/sqrt(640)
    for (int i = t; i < HLINES*640; i += 256){
        int l = i / 640, k = i - l*640;
        float2 v = X[l*HP + k];
        float s = (k & 1) ? -sc : sc;              // (-1)^k
        A2[base + i] = make_float2(v.x*s, v.y*s);
    }
}

// ---------------------------------------------------------------------------
// K3 (fused tail): B-axis FFT8 + magnitude + fp16-emulated conv2(1x1) + leaky
//                  + conv3x3(1->1, pad1) + leaky -> d_out.
// A2 is transposed [b][w][h]: pass 1a reads it h-coalesced (mag into Pl);
// pass 1b reads img w-coalesced and applies conv2; stage 2 conv from LDS.
// ---------------------------------------------------------------------------
__global__ __launch_bounds__(256) void tail_kernel(const float2* __restrict__ A2,
                                  const float* __restrict__ img,
                                  const float* __restrict__ w2,
                                  const float* __restrict__ b2,
                                  const float* __restrict__ wi,
                                  const float* __restrict__ bi,
                                  float* __restrict__ out){
    __shared__ float Pl[8][TS+2][TS+3];            // pitch 19: 2-way banks
    int t = threadIdx.x;
    int ty0 = (blockIdx.x / 23) * TS;              // 40 tiles over h
    int tx0 = (blockIdx.x % 23) * TS;              // 23 tiles over w

    float w2h0 = __half2float(__float2half(w2[0]));
    float w2h1 = __half2float(__float2half(w2[1]));
    float b2h  = __half2float(__float2half(b2[0]));
    const float sc8 = 0.35355339059327373f;        // 1/sqrt(8)

    // pass 1a: |centered ifft8| from A2, lanes sweep h (coalesced runs)
    for (int idx = t; idx < (TS+2)*(TS+2); idx += 256){
        int hx = idx / (TS+2), hy = idx - hx*(TS+2);
        int hh = ty0 - 1 + hy, ww = tx0 - 1 + hx;
        int hc = min(max(hh, 0), H_-1), wc = min(max(ww, 0), W_-1);
        float2 x[8], Xo[8];
        #pragma unroll
        for (int n = 0; n < 8; ++n){
            float2 v = A2[((size_t)(n*368 + wc))*640 + hc];
            float s = (n & 1) ? -1.f : 1.f;        // (-1)^n
            x[n] = make_float2(v.x*s, v.y*s);
        }
        fft8p_(x, Xo);
        #pragma unroll
        for (int k = 0; k < 8; ++k){
            float s = (k & 1) ? -sc8 : sc8;        // (-1)^k / sqrt(8)
            float yr = Xo[k].x * s, yi = Xo[k].y * s;
            float mag = sqrtf(yr*yr + yi*yi);
            Pl[k][hy][hx] = __half2float(__float2half(mag));
        }
    }
    __syncthreads();

    // pass 1b: conv2 with img, lanes sweep w (coalesced img reads)
    for (int idx = t; idx < (TS+2)*(TS+2); idx += 256){
        int hy = idx / (TS+2), hx = idx - hy*(TS+2);
        int hh = ty0 - 1 + hy, ww = tx0 - 1 + hx;
        bool inb = (hh >= 0) && (hh < H_) && (ww >= 0) && (ww < W_);
        int hc = min(max(hh, 0), H_-1), wc = min(max(ww, 0), W_-1);
        float inbf = inb ? 1.f : 0.f;
        #pragma unroll
        for (int k = 0; k < 8; ++k){
            float g = __half2float(__float2half(img[(size_t)k*HW_ + hc*W_ + wc]));
            float a = Pl[k][hy][hx];
            float o = leaky_(a*w2h0 + g*w2h1 + b2h);
            o = __half2float(__float2half(o));
            Pl[k][hy][hx] = o * inbf;              // zero-pad outside image
        }
    }
    __syncthreads();

    // stage 2: conv3x3 from LDS, 256 spatial px x 8 batch per block
    int sy = t >> 4, sx = t & 15;
    float wv[9];
    #pragma unroll
    for (int q = 0; q < 9; ++q) wv[q] = wi[q];
    float bi0 = bi[0];
    #pragma unroll
    for (int k = 0; k < 8; ++k){
        float acc = bi0;
        #pragma unroll
        for (int dy = 0; dy < 3; ++dy)
            #pragma unroll
            for (int dx = 0; dx < 3; ++dx)
                acc += wv[dy*3+dx] * Pl[k][sy+dy][sx+dx];
        out[((size_t)k*H_ + ty0+sy)*W_ + tx0+sx] = leaky_(acc);
    }
}

// ---------------------------------------------------------------------------
// Workspace layout (bytes):
//   Bt     : float2[NP]    @ 0            (15,073,280)   [b][w][h]
//   A2     : float2[NP]    @ 15,073,280   (15,073,280)   [b][w][h]
//   tables : float2[1301]  @ 30,146,560   (10,408)
// ---------------------------------------------------------------------------
extern "C" void kernel_launch(void* const* d_in, const int* in_sizes, int n_in,
                              void* d_out, int out_size, void* d_ws, size_t ws_size,
                              hipStream_t stream){
    const float* img = (const float*)d_in[0];
    const float* ksp = (const float*)d_in[1];
    const float* wk  = (const float*)d_in[2];
    const float* bk  = (const float*)d_in[3];
    const float* w1  = (const float*)d_in[4];
    const float* b1  = (const float*)d_in[5];
    const float* w2  = (const float*)d_in[6];
    const float* b2  = (const float*)d_in[7];
    const float* wi  = (const float*)d_in[8];
    const float* bi  = (const float*)d_in[9];

    char* ws = (char*)d_ws;
    float2* Bt  = (float2*)(ws + 0);
    float2* A2  = (float2*)(ws + 15073280);
    float2* T   = (float2*)(ws + 30146560);
    float2* TW368P = T + 0;
    float2* TW640P = T + 368;
    float2* TW40P  = T + 1008;
    float2* F23P   = T + 1048;
    float* out  = (float*)d_out;

    init_tables_kernel<<<6, 256, 0, stream>>>(T);

    kfftw_kernel<<<B_*(H_/FROWS), 256, 0, stream>>>(ksp, wk, bk, w1, b1,
                                                    TW368P, F23P, Bt);
    fftH_kernel<<<(B_*W_)/HLINES, 256, 0, stream>>>(Bt, TW640P, TW40P, A2);
    tail_kernel<<<(H_/TS)*(W_/TS), 256, 0, stream>>>(A2, img, w2, b2, wi, bi, out);
}